// Round 12
// baseline (346.317 us; speedup 1.0000x reference)
//
#include <hip/hip_runtime.h>
#include <hip/hip_bf16.h>
#include <math.h>

// ---------------------------------------------------------------------------
// GAT 3-layer forward, MI355X.
// GEMM L1/L2: fp16 single (MFMA f16, K=128/256). GEMM L3: bf16 hi/lo (K=512).
//   128-wide tiles, 2-phase pipeline, global_load_lds w16, T2 swizzle,
//   fused alpha epilogue.
// Aggregation: counting-sorted edges, per-node edge lists SORTED BY SRC
//   (bitonic, one wave/node) so concurrent waves walk a narrow sliding
//   window of the feature table -> per-XCD L2 holds it. 2 nodes/wave,
//   16B/lane fp16 gathers, 4-way edge unroll.
// ---------------------------------------------------------------------------

typedef __bf16 bf16x8 __attribute__((ext_vector_type(8)));
typedef float f32x4 __attribute__((ext_vector_type(4)));
typedef _Float16 half8v __attribute__((ext_vector_type(8)));
typedef _Float16 half4v __attribute__((ext_vector_type(4)));

#define MPAD 50048
#define QINV 2048.0f          // 32768 / 16
#define QDQ  4.8828125e-4f    // 16 / 32768

__device__ __forceinline__ void gload_lds16(const void* g, void* l) {
  __builtin_amdgcn_global_load_lds(
      (const __attribute__((address_space(1))) unsigned int*)g,
      (__attribute__((address_space(3))) unsigned int*)l, 16, 0, 0);
}

__device__ __forceinline__ unsigned int splitf(float a) {
  __hip_bfloat16 h = __float2bfloat16(a);
  float hf = __bfloat162float(h);
  __hip_bfloat16 l = __float2bfloat16(a - hf);
  return (unsigned int)__builtin_bit_cast(unsigned short, h) |
         ((unsigned int)__builtin_bit_cast(unsigned short, l) << 16);
}

__device__ __forceinline__ float leaky02(float l) {
  return (l >= 0.f) ? l : 0.2f * l;
}

__device__ __forceinline__ short quant16(float v) {
  int q = (int)rintf(v * QINV);
  q = q > 32767 ? 32767 : (q < -32768 ? -32768 : q);
  return (short)q;
}

// ---------------- edge sort ----------------

__global__ void hist_kernel(const int* __restrict__ dst, int e, int* counts) {
  int i = blockIdx.x * blockDim.x + threadIdx.x;
  if (i < e) atomicAdd(&counts[dst[i]], 1);
}

// counts[] holds edge-histogram (self-loop accounted as +1 here)
__global__ __launch_bounds__(1024) void block_sum_kernel(const int* __restrict__ counts,
                                                         int* __restrict__ bsum, int n) {
  __shared__ int red[1024];
  int i = blockIdx.x * 1024 + threadIdx.x;
  red[threadIdx.x] = (i < n) ? (counts[i] + 1) : 0;
  __syncthreads();
  #pragma unroll
  for (int off = 512; off > 0; off >>= 1) {
    if (threadIdx.x < off) red[threadIdx.x] += red[threadIdx.x + off];
    __syncthreads();
  }
  if (threadIdx.x == 0) bsum[blockIdx.x] = red[0];
}

__global__ void scan_sums_kernel(int* bsum, int nb) {
  int t = threadIdx.x;
  int c = (t < nb) ? bsum[t] : 0;
  int v = c;
  #pragma unroll
  for (int off = 1; off < 64; off <<= 1) {
    int u = __shfl_up(v, off);
    if (t >= off) v += u;
  }
  if (t < nb) bsum[t] = v - c;  // exclusive base
}

__global__ __launch_bounds__(1024) void scan_final_kernel(const int* __restrict__ counts,
    const int* __restrict__ bsum, int* __restrict__ offsets, int* __restrict__ cursor, int n) {
  __shared__ int sc[1024];
  int i = blockIdx.x * 1024 + threadIdx.x;
  int c = (i < n) ? (counts[i] + 1) : 0;
  sc[threadIdx.x] = c;
  __syncthreads();
  for (int off = 1; off < 1024; off <<= 1) {
    int v = 0;
    if (threadIdx.x >= off) v = sc[threadIdx.x - off];
    __syncthreads();
    sc[threadIdx.x] += v;
    __syncthreads();
  }
  int excl = sc[threadIdx.x] - c + bsum[blockIdx.x];
  if (i < n) {
    offsets[i] = excl;
    cursor[i] = excl;
  } else if (i == n) {
    offsets[n] = excl;
  }
}

__global__ void scatter_kernel(const int* __restrict__ src, const int* __restrict__ dst,
                               int e800, int etot, int* cursor, int* __restrict__ ssrc) {
  int i = blockIdx.x * blockDim.x + threadIdx.x;
  if (i >= etot) return;
  int s, d;
  if (i < e800) { s = src[i]; d = dst[i]; }
  else          { s = i - e800; d = s; }
  int pos = atomicAdd(&cursor[d], 1);
  ssrc[pos] = s;
}

// per-node src-sort (perf hint: sliding-window L2 locality). One wave/node,
// bitonic-64 via shfl_xor; rare deg>64 left unsorted (still correct).
__global__ __launch_bounds__(256) void sortseg_kernel(const int* __restrict__ offsets,
                                                      int* __restrict__ ssrc, int n) {
  int wid = threadIdx.x >> 6;
  int lane = threadIdx.x & 63;
  int node = blockIdx.x * 4 + wid;
  if (node >= n) return;
  int beg = offsets[node], end = offsets[node + 1];
  int deg = end - beg;
  if (deg > 64 || deg < 3) return;
  int v = (lane < deg) ? ssrc[beg + lane] : 0x7fffffff;
  #pragma unroll
  for (int k = 2; k <= 64; k <<= 1) {
    #pragma unroll
    for (int j = k >> 1; j > 0; j >>= 1) {
      int other = __shfl_xor(v, j);
      bool up = ((lane & k) == 0);
      bool lower = ((lane & j) == 0);
      int mn = min(v, other), mx = max(v, other);
      v = (lower == up) ? mn : mx;
    }
  }
  if (lane < deg) ssrc[beg + lane] = v;
}

// ---------------- input converts (x + all weights, one launch) --------------
__global__ void cvt_all_kernel(const float* __restrict__ x, const float* __restrict__ W1,
                               const float* __restrict__ W2, const float* __restrict__ W3,
                               _Float16* __restrict__ x16, _Float16* __restrict__ o1,
                               _Float16* __restrict__ o2, uint4* __restrict__ o3, int nx4) {
  int i = blockIdx.x * blockDim.x + threadIdx.x;
  if (i < nx4) {
    float4 v = reinterpret_cast<const float4*>(x)[i];
    half4v h = {(_Float16)v.x, (_Float16)v.y, (_Float16)v.z, (_Float16)v.w};
    *reinterpret_cast<half4v*>(x16 + (size_t)i * 4) = h;
    return;
  }
  int j = i - nx4;
  if (j < 8192) {
    float4 v = reinterpret_cast<const float4*>(W1)[j];
    half4v h = {(_Float16)v.x, (_Float16)v.y, (_Float16)v.z, (_Float16)v.w};
    *reinterpret_cast<half4v*>(o1 + (size_t)j * 4) = h;
  } else if (j < 8192 + 16384) {
    int k = j - 8192;
    float4 v = reinterpret_cast<const float4*>(W2)[k];
    half4v h = {(_Float16)v.x, (_Float16)v.y, (_Float16)v.z, (_Float16)v.w};
    *reinterpret_cast<half4v*>(o2 + (size_t)k * 4) = h;
  } else if (j < 8192 + 16384 + 4096) {
    int k = j - (8192 + 16384);
    float4 v = reinterpret_cast<const float4*>(W3)[k];
    uint4 o;
    o.x = splitf(v.x); o.y = splitf(v.y); o.z = splitf(v.z); o.w = splitf(v.w);
    o3[k] = o;
  }
}

// ---------------- MFMA GEMM + fused alpha epilogue ----------------
template <int KP, int BM, int BN, int WAVES_M, int WAVES_N, int OTOT, int HEADS,
          bool F16IN, bool F16OUT>
__global__ __launch_bounds__(256) void gemm2_kernel(
    const unsigned short* __restrict__ A, const unsigned short* __restrict__ B,
    void* __restrict__ Cq, const float* __restrict__ a_s, const float* __restrict__ a_d,
    float* __restrict__ asrcO, float* __restrict__ adstO, int M) {
  constexpr int BK = 64;
  constexpr int NK = KP / BK;
  constexpr int MFRAG = BM / WAVES_M / 16;
  constexpr int NFRAG = BN / WAVES_N / 16;
  __shared__ unsigned short As[2][BM * BK];
  __shared__ unsigned short Bs[2][BN * BK];

  const int tid = threadIdx.x;
  const int lane = tid & 63;
  const int wid = tid >> 6;
  const int m0 = blockIdx.x * BM;
  const int o0 = blockIdx.y * BN;

  const int srow = tid >> 3;
  const int scolb = (tid & 7) * 16;
  const int sswz = (srow & 7) << 4;
  const char* aSrc = (const char*)A + (size_t)(m0 + srow) * (KP * 2) + (scolb ^ sswz);
  const char* bSrc = (const char*)B + (size_t)(o0 + srow) * (KP * 2) + (scolb ^ sswz);
  char* aDst0 = (char*)&As[0][0] + wid * 1024;
  char* bDst0 = (char*)&Bs[0][0] + wid * 1024;

  auto stage = [&](int buf, int kt) {
    const size_t ko = (size_t)kt * 128;
    char* ad = aDst0 + buf * (BM * 128);
    #pragma unroll
    for (int i = 0; i < BM / 32; ++i)
      gload_lds16(aSrc + ko + (size_t)i * 32 * (KP * 2), ad + i * 4096);
    char* bd = bDst0 + buf * (BN * 128);
    #pragma unroll
    for (int j = 0; j < BN / 32; ++j)
      gload_lds16(bSrc + ko + (size_t)j * 32 * (KP * 2), bd + j * 4096);
  };

  const int fr = lane & 15;
  const int fg = lane >> 4;
  const int fswz = (fr & 7) << 4;
  const int wm0 = (wid / WAVES_N) * (BM / WAVES_M);
  const int wn0 = (wid % WAVES_N) * (BN / WAVES_N);

  f32x4 acc[MFRAG][NFRAG];
  #pragma unroll
  for (int mi = 0; mi < MFRAG; ++mi)
    #pragma unroll
    for (int ni = 0; ni < NFRAG; ++ni) acc[mi][ni] = (f32x4)0.f;

  stage(0, 0);
  __syncthreads();

  for (int kt = 0; kt < NK; ++kt) {
    const int buf = kt & 1;
    if (kt + 1 < NK) stage(buf ^ 1, kt + 1);
    const char* asB = (const char*)&As[buf][0] + (wm0 + fr) * 128;
    const char* bsB = (const char*)&Bs[buf][0] + (wn0 + fr) * 128;
    #pragma unroll
    for (int kh = 0; kh < 2; ++kh) {
      const int kb = (kh * 64 + fg * 16) ^ fswz;
      if constexpr (F16IN) {
        half8v af[MFRAG], bfr[NFRAG];
        #pragma unroll
        for (int mi = 0; mi < MFRAG; ++mi)
          af[mi] = *reinterpret_cast<const half8v*>(asB + mi * 16 * 128 + kb);
        #pragma unroll
        for (int ni = 0; ni < NFRAG; ++ni)
          bfr[ni] = *reinterpret_cast<const half8v*>(bsB + ni * 16 * 128 + kb);
        #pragma unroll
        for (int mi = 0; mi < MFRAG; ++mi)
          #pragma unroll
          for (int ni = 0; ni < NFRAG; ++ni)
            acc[mi][ni] = __builtin_amdgcn_mfma_f32_16x16x32_f16(af[mi], bfr[ni], acc[mi][ni], 0, 0, 0);
      } else {
        bf16x8 af[MFRAG], bfr[NFRAG];
        #pragma unroll
        for (int mi = 0; mi < MFRAG; ++mi)
          af[mi] = *reinterpret_cast<const bf16x8*>(asB + mi * 16 * 128 + kb);
        #pragma unroll
        for (int ni = 0; ni < NFRAG; ++ni)
          bfr[ni] = *reinterpret_cast<const bf16x8*>(bsB + ni * 16 * 128 + kb);
        #pragma unroll
        for (int mi = 0; mi < MFRAG; ++mi)
          #pragma unroll
          for (int ni = 0; ni < NFRAG; ++ni)
            acc[mi][ni] = __builtin_amdgcn_mfma_f32_16x16x32_bf16(af[mi], bfr[ni], acc[mi][ni], 0, 0, 0);
      }
    }
    __syncthreads();
  }

  // fused alpha + quantized store (wave's 64 cols lie in one head when HEADS=4)
  const int head = (HEADS == 4) ? ((o0 + wn0) >> 6) : 0;
  float asl[NFRAG], adl[NFRAG];
  #pragma unroll
  for (int ni = 0; ni < NFRAG; ++ni) {
    int c64 = (HEADS == 4) ? (ni * 16 + fr) : (wn0 + ni * 16 + fr);
    asl[ni] = a_s[head * 64 + c64];
    adl[ni] = a_d[head * 64 + c64];
  }
  #pragma unroll
  for (int mi = 0; mi < MFRAG; ++mi) {
    #pragma unroll
    for (int r = 0; r < 4; ++r) {
      int row = m0 + wm0 + mi * 16 + fg * 4 + r;
      float ps = 0.f, pd = 0.f;
      #pragma unroll
      for (int ni = 0; ni < NFRAG; ++ni) {
        ps = fmaf(acc[mi][ni][r], asl[ni], ps);
        pd = fmaf(acc[mi][ni][r], adl[ni], pd);
      }
      #pragma unroll
      for (int off = 1; off < 16; off <<= 1) {
        ps += __shfl_xor(ps, off);
        pd += __shfl_xor(pd, off);
      }
      if (row < M) {
        if (fr == 0) {
          asrcO[(size_t)row * HEADS + head] = ps;
          adstO[(size_t)row * HEADS + head] = pd;
        }
        #pragma unroll
        for (int ni = 0; ni < NFRAG; ++ni) {
          size_t ci = (size_t)row * OTOT + o0 + wn0 + ni * 16 + fr;
          if constexpr (F16OUT) ((_Float16*)Cq)[ci] = (_Float16)acc[mi][ni][r];
          else                  ((short*)Cq)[ci] = quant16(acc[mi][ni][r]);
        }
      }
    }
  }
}

// ---------------- aggregation, HEADS=4: 2 nodes/wave, 4-way edge unroll -----
template <bool OUTBF>
__global__ __launch_bounds__(256) void aggregate4_kernel(
    const _Float16* __restrict__ hq, const float* __restrict__ asrc,
    const float* __restrict__ adst, const float* __restrict__ bias,
    const int* __restrict__ offsets, const int* __restrict__ ssrc,
    void* __restrict__ outp, int n) {
  int wid = threadIdx.x >> 6;
  int lane = threadIdx.x & 63;
  int sub = lane >> 5;          // which of the 2 nodes in this wave
  int hl = lane & 31;           // 32 lanes per node; 8 channels each
  int node = blockIdx.x * 8 + wid * 2 + sub;
  if (node >= n) return;
  int head = hl >> 3;           // 8 lanes per head
  int ch8 = hl * 8;
  float adv = adst[(size_t)node * 4 + head];
  int beg = offsets[node], end = offsets[node + 1];

  float s0 = 0.f, s1 = 0.f, s2 = 0.f, s3 = 0.f;
  float A0[8] = {}, A1[8] = {}, A2[8] = {}, A3[8] = {};
  int e = beg;
  for (; e + 3 < end; e += 4) {
    int c0 = ssrc[e + 0], c1 = ssrc[e + 1], c2 = ssrc[e + 2], c3 = ssrc[e + 3];
    float p0 = __expf(leaky02(asrc[(size_t)c0 * 4 + head] + adv));
    float p1 = __expf(leaky02(asrc[(size_t)c1 * 4 + head] + adv));
    float p2 = __expf(leaky02(asrc[(size_t)c2 * 4 + head] + adv));
    float p3 = __expf(leaky02(asrc[(size_t)c3 * 4 + head] + adv));
    half8v h0 = *reinterpret_cast<const half8v*>(&hq[(size_t)c0 * 256 + ch8]);
    half8v h1 = *reinterpret_cast<const half8v*>(&hq[(size_t)c1 * 256 + ch8]);
    half8v h2 = *reinterpret_cast<const half8v*>(&hq[(size_t)c2 * 256 + ch8]);
    half8v h3 = *reinterpret_cast<const half8v*>(&hq[(size_t)c3 * 256 + ch8]);
    s0 += p0; s1 += p1; s2 += p2; s3 += p3;
    #pragma unroll
    for (int j = 0; j < 8; ++j) {
      A0[j] = fmaf((float)h0[j], p0, A0[j]);
      A1[j] = fmaf((float)h1[j], p1, A1[j]);
      A2[j] = fmaf((float)h2[j], p2, A2[j]);
      A3[j] = fmaf((float)h3[j], p3, A3[j]);
    }
  }
  for (; e < end; ++e) {
    int c0 = ssrc[e];
    float p0 = __expf(leaky02(asrc[(size_t)c0 * 4 + head] + adv));
    half8v h0 = *reinterpret_cast<const half8v*>(&hq[(size_t)c0 * 256 + ch8]);
    s0 += p0;
    #pragma unroll
    for (int j = 0; j < 8; ++j) A0[j] = fmaf((float)h0[j], p0, A0[j]);
  }
  float s = (s0 + s1) + (s2 + s3);
  float A[8];
  #pragma unroll
  for (int j = 0; j < 8; ++j) A[j] = (A0[j] + A1[j]) + (A2[j] + A3[j]);

  float inv = 1.f / (s + 1e-16f);
  float4 bv0 = *reinterpret_cast<const float4*>(&bias[ch8]);
  float4 bv1 = *reinterpret_cast<const float4*>(&bias[ch8 + 4]);
  float o[8];
  o[0] = fmaxf(A[0] * inv + bv0.x, 0.f);
  o[1] = fmaxf(A[1] * inv + bv0.y, 0.f);
  o[2] = fmaxf(A[2] * inv + bv0.z, 0.f);
  o[3] = fmaxf(A[3] * inv + bv0.w, 0.f);
  o[4] = fmaxf(A[4] * inv + bv1.x, 0.f);
  o[5] = fmaxf(A[5] * inv + bv1.y, 0.f);
  o[6] = fmaxf(A[6] * inv + bv1.z, 0.f);
  o[7] = fmaxf(A[7] * inv + bv1.w, 0.f);
  if (OUTBF) {
    uint4 pk0, pk1;
    pk0.x = splitf(o[0]); pk0.y = splitf(o[1]); pk0.z = splitf(o[2]); pk0.w = splitf(o[3]);
    pk1.x = splitf(o[4]); pk1.y = splitf(o[5]); pk1.z = splitf(o[6]); pk1.w = splitf(o[7]);
    reinterpret_cast<uint4*>(outp)[(size_t)node * 64 + hl * 2 + 0] = pk0;
    reinterpret_cast<uint4*>(outp)[(size_t)node * 64 + hl * 2 + 1] = pk1;
  } else {
    half8v hv;
    #pragma unroll
    for (int j = 0; j < 8; ++j) hv[j] = (_Float16)o[j];
    *reinterpret_cast<half8v*>((_Float16*)outp + (size_t)node * 256 + ch8) = hv;
  }
}

// ---------------- aggregation, HEADS=1: single-pass, int16 gathers ----------
__global__ __launch_bounds__(256) void aggregate1_kernel(
    const short* __restrict__ hq, const float* __restrict__ asrc,
    const float* __restrict__ adst, const float* __restrict__ bias,
    const int* __restrict__ offsets, const int* __restrict__ ssrc,
    float* __restrict__ out, int n) {
  int wid = threadIdx.x >> 6;
  int lane = threadIdx.x & 63;
  int node = blockIdx.x * 4 + wid;
  if (node >= n) return;
  int g = lane >> 4;       // edge substream 0..3
  int w = lane & 15;       // channel quad
  float adv = adst[node];
  int beg = offsets[node], end = offsets[node + 1];

  float s = 0.f;
  float4 A = {0, 0, 0, 0};
  int e0 = beg;
  for (; e0 + 3 < end; e0 += 4) {
    int src = ssrc[e0 + g];
    float p = __expf(leaky02(asrc[src] + adv));
    short4 q = *reinterpret_cast<const short4*>(&hq[(size_t)src * 64 + w * 4]);
    s += p;
    A.x += p * (float)q.x; A.y += p * (float)q.y;
    A.z += p * (float)q.z; A.w += p * (float)q.w;
  }
  if (e0 + g < end) {
    int src = ssrc[e0 + g];
    float p = __expf(leaky02(asrc[src] + adv));
    short4 q = *reinterpret_cast<const short4*>(&hq[(size_t)src * 64 + w * 4]);
    s += p;
    A.x += p * (float)q.x; A.y += p * (float)q.y;
    A.z += p * (float)q.z; A.w += p * (float)q.w;
  }
  #pragma unroll
  for (int off = 16; off < 64; off <<= 1) {
    s += __shfl_xor(s, off);
    A.x += __shfl_xor(A.x, off);
    A.y += __shfl_xor(A.y, off);
    A.z += __shfl_xor(A.z, off);
    A.w += __shfl_xor(A.w, off);
  }
  if (g == 0) {
    float inv = QDQ / (s + 1e-16f);
    float4 bv = *reinterpret_cast<const float4*>(&bias[w * 4]);
    float4 o;
    o.x = A.x * inv + bv.x;
    o.y = A.y * inv + bv.y;
    o.z = A.z * inv + bv.z;
    o.w = A.w * inv + bv.w;
    *reinterpret_cast<float4*>(&out[(size_t)node * 64 + w * 4]) = o;
  }
}

// ---------------- launch ----------------

extern "C" void kernel_launch(void* const* d_in, const int* in_sizes, int n_in,
                              void* d_out, int out_size, void* d_ws, size_t ws_size,
                              hipStream_t stream) {
  const float* x   = (const float*)d_in[0];
  const int*   ei  = (const int*)d_in[1];
  const float* W1  = (const float*)d_in[2];
  const float* as1 = (const float*)d_in[3];
  const float* ad1 = (const float*)d_in[4];
  const float* b1  = (const float*)d_in[5];
  const float* W2  = (const float*)d_in[6];
  const float* as2 = (const float*)d_in[7];
  const float* ad2 = (const float*)d_in[8];
  const float* b2  = (const float*)d_in[9];
  const float* W3  = (const float*)d_in[10];
  const float* as3 = (const float*)d_in[11];
  const float* ad3 = (const float*)d_in[12];
  const float* b3  = (const float*)d_in[13];
  float* out = (float*)d_out;

  const int n    = in_sizes[0] / 128;  // 50000
  const int e800 = in_sizes[1] / 2;    // 800000
  const int etot = e800 + n;

  char* ws = (char*)d_ws;
  size_t off = 0;
  auto alloc = [&](size_t bytes) -> void* {
    void* p = ws + off;
    off = (off + bytes + 255) & ~(size_t)255;
    return p;
  };
  _Float16*       x16      = (_Float16*)alloc((size_t)MPAD * 128 * 2);
  _Float16*       feat16   = (_Float16*)alloc((size_t)MPAD * 256 * 2);
  _Float16*       hagg16   = (_Float16*)alloc((size_t)MPAD * 256 * 2);
  unsigned short* hsplitBF = (unsigned short*)alloc((size_t)MPAD * 512 * 2);
  short*          featL3   = (short*)alloc((size_t)MPAD * 64 * 2);
  _Float16*       w1f      = (_Float16*)alloc((size_t)256 * 128 * 2);
  _Float16*       w2f      = (_Float16*)alloc((size_t)256 * 256 * 2);
  unsigned short* w3s      = (unsigned short*)alloc((size_t)64 * 512 * 2);
  float* asrc    = (float*)alloc((size_t)n * 4 * 4);
  float* adst    = (float*)alloc((size_t)n * 4 * 4);
  int*   ssrc    = (int*)alloc((size_t)(etot + 4) * 4);
  int*   offsets = (int*)alloc((size_t)(n + 1) * 4);
  int*   cursor  = (int*)alloc((size_t)n * 4);
  int*   counts  = (int*)alloc((size_t)n * 4);
  int*   bsum    = (int*)alloc((size_t)64 * 4);

  const int* esrc = ei;
  const int* edst = ei + e800;
  const int nbScan = (n + 1024) / 1024;

  hipMemsetAsync(counts, 0, (size_t)n * 4, stream);
  hist_kernel<<<(e800 + 255) / 256, 256, 0, stream>>>(edst, e800, counts);
  block_sum_kernel<<<nbScan, 1024, 0, stream>>>(counts, bsum, n);
  scan_sums_kernel<<<1, 64, 0, stream>>>(bsum, nbScan);
  scan_final_kernel<<<nbScan, 1024, 0, stream>>>(counts, bsum, offsets, cursor, n);
  scatter_kernel<<<(etot + 255) / 256, 256, 0, stream>>>(esrc, edst, e800, etot, cursor, ssrc);
  sortseg_kernel<<<(n + 3) / 4, 256, 0, stream>>>(offsets, ssrc, n);

  const int nx4 = n * 128 / 4;
  cvt_all_kernel<<<(nx4 + 28672 + 255) / 256, 256, 0, stream>>>(
      x, W1, W2, W3, x16, w1f, w2f, (uint4*)w3s, nx4);

  const int mBlocks = MPAD / 128;  // 391

  // layer 1: fp16 GEMM K=128, alpha fused, fp16 [node][256] out
  gemm2_kernel<128, 128, 128, 2, 2, 256, 4, true, true><<<dim3(mBlocks, 2), 256, 0, stream>>>(
      (const unsigned short*)x16, (const unsigned short*)w1f, feat16, as1, ad1, asrc, adst, n);
  aggregate4_kernel<false><<<(n + 7) / 8, 256, 0, stream>>>(
      feat16, asrc, adst, b1, offsets, ssrc, hagg16, n);

  // layer 2: fp16 GEMM K=256, alpha fused, fp16 [node][256] out
  gemm2_kernel<256, 128, 128, 2, 2, 256, 4, true, true><<<dim3(mBlocks, 2), 256, 0, stream>>>(
      (const unsigned short*)hagg16, (const unsigned short*)w2f, feat16, as2, ad2, asrc, adst, n);
  aggregate4_kernel<true><<<(n + 7) / 8, 256, 0, stream>>>(
      feat16, asrc, adst, b2, offsets, ssrc, hsplitBF, n);

  // layer 3: bf16 hi/lo GEMM K=512 (output accuracy), int16 features
  gemm2_kernel<512, 128, 64, 4, 1, 64, 1, false, false><<<dim3(mBlocks, 1), 256, 0, stream>>>(
      hsplitBF, w3s, featL3, as3, ad3, asrc, adst, n);
  aggregate1_kernel<<<(n + 3) / 4, 256, 0, stream>>>(
      featL3, asrc, adst, b3, offsets, ssrc, out, n);
}

// Round 13
// 329.149 us; speedup vs baseline: 1.0522x; 1.0522x over previous
//
#include <hip/hip_runtime.h>
#include <hip/hip_bf16.h>
#include <math.h>

// ---------------------------------------------------------------------------
// GAT 3-layer forward, MI355X.
// All GEMMs fp16-single MFMA (L1 K=128, L2 K=256, L3 K=256), 128-wide tiles,
//   2-phase pipeline, global_load_lds w16, T2 swizzle, fused alpha epilogue.
//   L3 epilogue quantizes features to int16 (scale 16/32768).
// Aggregation (R9/R11 structure -- measured best): one edge pass covers all
//   4 heads; 2 nodes/wave, 16B/lane fp16 gathers, 4-way edge unroll.
//   agg4 is at its compulsory per-XCD L2-miss floor (FETCH = table x 8 XCD).
// Edge sort: hist + hierarchical scan + scatter (shared by all layers).
// ---------------------------------------------------------------------------

typedef float f32x4 __attribute__((ext_vector_type(4)));
typedef _Float16 half8v __attribute__((ext_vector_type(8)));
typedef _Float16 half4v __attribute__((ext_vector_type(4)));

#define MPAD 50048
#define QINV 2048.0f          // 32768 / 16
#define QDQ  4.8828125e-4f    // 16 / 32768

__device__ __forceinline__ void gload_lds16(const void* g, void* l) {
  __builtin_amdgcn_global_load_lds(
      (const __attribute__((address_space(1))) unsigned int*)g,
      (__attribute__((address_space(3))) unsigned int*)l, 16, 0, 0);
}

__device__ __forceinline__ float leaky02(float l) {
  return (l >= 0.f) ? l : 0.2f * l;
}

__device__ __forceinline__ short quant16(float v) {
  int q = (int)rintf(v * QINV);
  q = q > 32767 ? 32767 : (q < -32768 ? -32768 : q);
  return (short)q;
}

// ---------------- edge sort ----------------

__global__ void hist_kernel(const int* __restrict__ dst, int e, int* counts) {
  int i = blockIdx.x * blockDim.x + threadIdx.x;
  if (i < e) atomicAdd(&counts[dst[i]], 1);
}

// counts[] holds edge-histogram (self-loop accounted as +1 in readers)
__global__ __launch_bounds__(1024) void block_sum_kernel(const int* __restrict__ counts,
                                                         int* __restrict__ bsum, int n) {
  __shared__ int red[1024];
  int i = blockIdx.x * 1024 + threadIdx.x;
  red[threadIdx.x] = (i < n) ? (counts[i] + 1) : 0;
  __syncthreads();
  #pragma unroll
  for (int off = 512; off > 0; off >>= 1) {
    if (threadIdx.x < off) red[threadIdx.x] += red[threadIdx.x + off];
    __syncthreads();
  }
  if (threadIdx.x == 0) bsum[blockIdx.x] = red[0];
}

__global__ void scan_sums_kernel(int* bsum, int nb) {
  int t = threadIdx.x;
  int c = (t < nb) ? bsum[t] : 0;
  int v = c;
  #pragma unroll
  for (int off = 1; off < 64; off <<= 1) {
    int u = __shfl_up(v, off);
    if (t >= off) v += u;
  }
  if (t < nb) bsum[t] = v - c;  // exclusive base
}

__global__ __launch_bounds__(1024) void scan_final_kernel(const int* __restrict__ counts,
    const int* __restrict__ bsum, int* __restrict__ offsets, int* __restrict__ cursor, int n) {
  __shared__ int sc[1024];
  int i = blockIdx.x * 1024 + threadIdx.x;
  int c = (i < n) ? (counts[i] + 1) : 0;
  sc[threadIdx.x] = c;
  __syncthreads();
  for (int off = 1; off < 1024; off <<= 1) {
    int v = 0;
    if (threadIdx.x >= off) v = sc[threadIdx.x - off];
    __syncthreads();
    sc[threadIdx.x] += v;
    __syncthreads();
  }
  int excl = sc[threadIdx.x] - c + bsum[blockIdx.x];
  if (i < n) {
    offsets[i] = excl;
    cursor[i] = excl;
  } else if (i == n) {
    offsets[n] = excl;
  }
}

__global__ void scatter_kernel(const int* __restrict__ src, const int* __restrict__ dst,
                               int e800, int etot, int* cursor, int* __restrict__ ssrc) {
  int i = blockIdx.x * blockDim.x + threadIdx.x;
  if (i >= etot) return;
  int s, d;
  if (i < e800) { s = src[i]; d = dst[i]; }
  else          { s = i - e800; d = s; }
  int pos = atomicAdd(&cursor[d], 1);
  ssrc[pos] = s;
}

// ---------------- input converts (x + all weights -> fp16, one launch) ------
__global__ void cvt_all_kernel(const float* __restrict__ x, const float* __restrict__ W1,
                               const float* __restrict__ W2, const float* __restrict__ W3,
                               _Float16* __restrict__ x16, _Float16* __restrict__ o1,
                               _Float16* __restrict__ o2, _Float16* __restrict__ o3, int nx4) {
  int i = blockIdx.x * blockDim.x + threadIdx.x;
  const float* in;
  _Float16* out;
  int j;
  if (i < nx4)                       { in = x;  out = x16; j = i; }
  else if ((j = i - nx4) < 8192)     { in = W1; out = o1; }
  else if ((j -= 8192) < 16384)      { in = W2; out = o2; }
  else if ((j -= 16384) < 4096)      { in = W3; out = o3; }
  else return;
  float4 v = reinterpret_cast<const float4*>(in)[j];
  half4v h = {(_Float16)v.x, (_Float16)v.y, (_Float16)v.z, (_Float16)v.w};
  *reinterpret_cast<half4v*>(out + (size_t)j * 4) = h;
}

// ---------------- MFMA GEMM (fp16) + fused alpha epilogue ----------------
// A: [MPAD][KP] fp16, B: [OTOT][KP] fp16. C: fp16 [row][OTOT] (F16OUT) or
// int16 [row][OTOT]. alpha_src/dst written per (row, head).
template <int KP, int BM, int BN, int WAVES_M, int WAVES_N, int OTOT, int HEADS, bool F16OUT>
__global__ __launch_bounds__(256) void gemm2_kernel(
    const _Float16* __restrict__ A, const _Float16* __restrict__ B,
    void* __restrict__ Cq, const float* __restrict__ a_s, const float* __restrict__ a_d,
    float* __restrict__ asrcO, float* __restrict__ adstO, int M) {
  constexpr int BK = 64;
  constexpr int NK = KP / BK;
  constexpr int MFRAG = BM / WAVES_M / 16;
  constexpr int NFRAG = BN / WAVES_N / 16;
  __shared__ _Float16 As[2][BM * BK];
  __shared__ _Float16 Bs[2][BN * BK];

  const int tid = threadIdx.x;
  const int lane = tid & 63;
  const int wid = tid >> 6;
  const int m0 = blockIdx.x * BM;
  const int o0 = blockIdx.y * BN;

  const int srow = tid >> 3;
  const int scolb = (tid & 7) * 16;
  const int sswz = (srow & 7) << 4;
  const char* aSrc = (const char*)A + (size_t)(m0 + srow) * (KP * 2) + (scolb ^ sswz);
  const char* bSrc = (const char*)B + (size_t)(o0 + srow) * (KP * 2) + (scolb ^ sswz);
  char* aDst0 = (char*)&As[0][0] + wid * 1024;
  char* bDst0 = (char*)&Bs[0][0] + wid * 1024;

  auto stage = [&](int buf, int kt) {
    const size_t ko = (size_t)kt * 128;
    char* ad = aDst0 + buf * (BM * 128);
    #pragma unroll
    for (int i = 0; i < BM / 32; ++i)
      gload_lds16(aSrc + ko + (size_t)i * 32 * (KP * 2), ad + i * 4096);
    char* bd = bDst0 + buf * (BN * 128);
    #pragma unroll
    for (int j = 0; j < BN / 32; ++j)
      gload_lds16(bSrc + ko + (size_t)j * 32 * (KP * 2), bd + j * 4096);
  };

  const int fr = lane & 15;
  const int fg = lane >> 4;
  const int fswz = (fr & 7) << 4;
  const int wm0 = (wid / WAVES_N) * (BM / WAVES_M);
  const int wn0 = (wid % WAVES_N) * (BN / WAVES_N);

  f32x4 acc[MFRAG][NFRAG];
  #pragma unroll
  for (int mi = 0; mi < MFRAG; ++mi)
    #pragma unroll
    for (int ni = 0; ni < NFRAG; ++ni) acc[mi][ni] = (f32x4)0.f;

  stage(0, 0);
  __syncthreads();

  for (int kt = 0; kt < NK; ++kt) {
    const int buf = kt & 1;
    if (kt + 1 < NK) stage(buf ^ 1, kt + 1);
    const char* asB = (const char*)&As[buf][0] + (wm0 + fr) * 128;
    const char* bsB = (const char*)&Bs[buf][0] + (wn0 + fr) * 128;
    #pragma unroll
    for (int kh = 0; kh < 2; ++kh) {
      const int kb = (kh * 64 + fg * 16) ^ fswz;
      half8v af[MFRAG], bfr[NFRAG];
      #pragma unroll
      for (int mi = 0; mi < MFRAG; ++mi)
        af[mi] = *reinterpret_cast<const half8v*>(asB + mi * 16 * 128 + kb);
      #pragma unroll
      for (int ni = 0; ni < NFRAG; ++ni)
        bfr[ni] = *reinterpret_cast<const half8v*>(bsB + ni * 16 * 128 + kb);
      #pragma unroll
      for (int mi = 0; mi < MFRAG; ++mi)
        #pragma unroll
        for (int ni = 0; ni < NFRAG; ++ni)
          acc[mi][ni] = __builtin_amdgcn_mfma_f32_16x16x32_f16(af[mi], bfr[ni], acc[mi][ni], 0, 0, 0);
    }
    __syncthreads();
  }

  // fused alpha + quantized store (wave's 64 cols lie in one head when HEADS=4)
  const int head = (HEADS == 4) ? ((o0 + wn0) >> 6) : 0;
  float asl[NFRAG], adl[NFRAG];
  #pragma unroll
  for (int ni = 0; ni < NFRAG; ++ni) {
    int c64 = (HEADS == 4) ? (ni * 16 + fr) : (wn0 + ni * 16 + fr);
    asl[ni] = a_s[head * 64 + c64];
    adl[ni] = a_d[head * 64 + c64];
  }
  #pragma unroll
  for (int mi = 0; mi < MFRAG; ++mi) {
    #pragma unroll
    for (int r = 0; r < 4; ++r) {
      int row = m0 + wm0 + mi * 16 + fg * 4 + r;
      float ps = 0.f, pd = 0.f;
      #pragma unroll
      for (int ni = 0; ni < NFRAG; ++ni) {
        ps = fmaf(acc[mi][ni][r], asl[ni], ps);
        pd = fmaf(acc[mi][ni][r], adl[ni], pd);
      }
      #pragma unroll
      for (int off = 1; off < 16; off <<= 1) {
        ps += __shfl_xor(ps, off);
        pd += __shfl_xor(pd, off);
      }
      if (row < M) {
        if (fr == 0) {
          asrcO[(size_t)row * HEADS + head] = ps;
          adstO[(size_t)row * HEADS + head] = pd;
        }
        #pragma unroll
        for (int ni = 0; ni < NFRAG; ++ni) {
          size_t ci = (size_t)row * OTOT + o0 + wn0 + ni * 16 + fr;
          if constexpr (F16OUT) ((_Float16*)Cq)[ci] = (_Float16)acc[mi][ni][r];
          else                  ((short*)Cq)[ci] = quant16(acc[mi][ni][r]);
        }
      }
    }
  }
}

// ---------------- aggregation, HEADS=4: 2 nodes/wave, 4-way edge unroll -----
// fp16 in, fp16 out (feeds next fp16 GEMM). Both agg4 layers have relu.
__global__ __launch_bounds__(256) void aggregate4_kernel(
    const _Float16* __restrict__ hq, const float* __restrict__ asrc,
    const float* __restrict__ adst, const float* __restrict__ bias,
    const int* __restrict__ offsets, const int* __restrict__ ssrc,
    _Float16* __restrict__ outp, int n) {
  int wid = threadIdx.x >> 6;
  int lane = threadIdx.x & 63;
  int sub = lane >> 5;          // which of the 2 nodes in this wave
  int hl = lane & 31;           // 32 lanes per node; 8 channels each
  int node = blockIdx.x * 8 + wid * 2 + sub;
  if (node >= n) return;
  int head = hl >> 3;           // 8 lanes per head
  int ch8 = hl * 8;
  float adv = adst[(size_t)node * 4 + head];
  int beg = offsets[node], end = offsets[node + 1];

  float s0 = 0.f, s1 = 0.f, s2 = 0.f, s3 = 0.f;
  float A0[8] = {}, A1[8] = {}, A2[8] = {}, A3[8] = {};
  int e = beg;
  for (; e + 3 < end; e += 4) {
    int c0 = ssrc[e + 0], c1 = ssrc[e + 1], c2 = ssrc[e + 2], c3 = ssrc[e + 3];
    float p0 = __expf(leaky02(asrc[(size_t)c0 * 4 + head] + adv));
    float p1 = __expf(leaky02(asrc[(size_t)c1 * 4 + head] + adv));
    float p2 = __expf(leaky02(asrc[(size_t)c2 * 4 + head] + adv));
    float p3 = __expf(leaky02(asrc[(size_t)c3 * 4 + head] + adv));
    half8v h0 = *reinterpret_cast<const half8v*>(&hq[(size_t)c0 * 256 + ch8]);
    half8v h1 = *reinterpret_cast<const half8v*>(&hq[(size_t)c1 * 256 + ch8]);
    half8v h2 = *reinterpret_cast<const half8v*>(&hq[(size_t)c2 * 256 + ch8]);
    half8v h3 = *reinterpret_cast<const half8v*>(&hq[(size_t)c3 * 256 + ch8]);
    s0 += p0; s1 += p1; s2 += p2; s3 += p3;
    #pragma unroll
    for (int j = 0; j < 8; ++j) {
      A0[j] = fmaf((float)h0[j], p0, A0[j]);
      A1[j] = fmaf((float)h1[j], p1, A1[j]);
      A2[j] = fmaf((float)h2[j], p2, A2[j]);
      A3[j] = fmaf((float)h3[j], p3, A3[j]);
    }
  }
  for (; e < end; ++e) {
    int c0 = ssrc[e];
    float p0 = __expf(leaky02(asrc[(size_t)c0 * 4 + head] + adv));
    half8v h0 = *reinterpret_cast<const half8v*>(&hq[(size_t)c0 * 256 + ch8]);
    s0 += p0;
    #pragma unroll
    for (int j = 0; j < 8; ++j) A0[j] = fmaf((float)h0[j], p0, A0[j]);
  }
  float s = (s0 + s1) + (s2 + s3);
  float A[8];
  #pragma unroll
  for (int j = 0; j < 8; ++j) A[j] = (A0[j] + A1[j]) + (A2[j] + A3[j]);

  float inv = 1.f / (s + 1e-16f);
  float4 bv0 = *reinterpret_cast<const float4*>(&bias[ch8]);
  float4 bv1 = *reinterpret_cast<const float4*>(&bias[ch8 + 4]);
  half8v hv;
  hv[0] = (_Float16)fmaxf(A[0] * inv + bv0.x, 0.f);
  hv[1] = (_Float16)fmaxf(A[1] * inv + bv0.y, 0.f);
  hv[2] = (_Float16)fmaxf(A[2] * inv + bv0.z, 0.f);
  hv[3] = (_Float16)fmaxf(A[3] * inv + bv0.w, 0.f);
  hv[4] = (_Float16)fmaxf(A[4] * inv + bv1.x, 0.f);
  hv[5] = (_Float16)fmaxf(A[5] * inv + bv1.y, 0.f);
  hv[6] = (_Float16)fmaxf(A[6] * inv + bv1.z, 0.f);
  hv[7] = (_Float16)fmaxf(A[7] * inv + bv1.w, 0.f);
  *reinterpret_cast<half8v*>(outp + (size_t)node * 256 + ch8) = hv;
}

// ---------------- aggregation, HEADS=1: single-pass, int16 gathers ----------
__global__ __launch_bounds__(256) void aggregate1_kernel(
    const short* __restrict__ hq, const float* __restrict__ asrc,
    const float* __restrict__ adst, const float* __restrict__ bias,
    const int* __restrict__ offsets, const int* __restrict__ ssrc,
    float* __restrict__ out, int n) {
  int wid = threadIdx.x >> 6;
  int lane = threadIdx.x & 63;
  int node = blockIdx.x * 4 + wid;
  if (node >= n) return;
  int g = lane >> 4;       // edge substream 0..3
  int w = lane & 15;       // channel quad
  float adv = adst[node];
  int beg = offsets[node], end = offsets[node + 1];

  float s = 0.f;
  float4 A = {0, 0, 0, 0};
  int e0 = beg;
  for (; e0 + 3 < end; e0 += 4) {
    int src = ssrc[e0 + g];
    float p = __expf(leaky02(asrc[src] + adv));
    short4 q = *reinterpret_cast<const short4*>(&hq[(size_t)src * 64 + w * 4]);
    s += p;
    A.x += p * (float)q.x; A.y += p * (float)q.y;
    A.z += p * (float)q.z; A.w += p * (float)q.w;
  }
  if (e0 + g < end) {
    int src = ssrc[e0 + g];
    float p = __expf(leaky02(asrc[src] + adv));
    short4 q = *reinterpret_cast<const short4*>(&hq[(size_t)src * 64 + w * 4]);
    s += p;
    A.x += p * (float)q.x; A.y += p * (float)q.y;
    A.z += p * (float)q.z; A.w += p * (float)q.w;
  }
  #pragma unroll
  for (int off = 16; off < 64; off <<= 1) {
    s += __shfl_xor(s, off);
    A.x += __shfl_xor(A.x, off);
    A.y += __shfl_xor(A.y, off);
    A.z += __shfl_xor(A.z, off);
    A.w += __shfl_xor(A.w, off);
  }
  if (g == 0) {
    float inv = QDQ / (s + 1e-16f);
    float4 bv = *reinterpret_cast<const float4*>(&bias[w * 4]);
    float4 o;
    o.x = A.x * inv + bv.x;
    o.y = A.y * inv + bv.y;
    o.z = A.z * inv + bv.z;
    o.w = A.w * inv + bv.w;
    *reinterpret_cast<float4*>(&out[(size_t)node * 64 + w * 4]) = o;
  }
}

// ---------------- launch ----------------

extern "C" void kernel_launch(void* const* d_in, const int* in_sizes, int n_in,
                              void* d_out, int out_size, void* d_ws, size_t ws_size,
                              hipStream_t stream) {
  const float* x   = (const float*)d_in[0];
  const int*   ei  = (const int*)d_in[1];
  const float* W1  = (const float*)d_in[2];
  const float* as1 = (const float*)d_in[3];
  const float* ad1 = (const float*)d_in[4];
  const float* b1  = (const float*)d_in[5];
  const float* W2  = (const float*)d_in[6];
  const float* as2 = (const float*)d_in[7];
  const float* ad2 = (const float*)d_in[8];
  const float* b2  = (const float*)d_in[9];
  const float* W3  = (const float*)d_in[10];
  const float* as3 = (const float*)d_in[11];
  const float* ad3 = (const float*)d_in[12];
  const float* b3  = (const float*)d_in[13];
  float* out = (float*)d_out;

  const int n    = in_sizes[0] / 128;  // 50000
  const int e800 = in_sizes[1] / 2;    // 800000
  const int etot = e800 + n;

  char* ws = (char*)d_ws;
  size_t off = 0;
  auto alloc = [&](size_t bytes) -> void* {
    void* p = ws + off;
    off = (off + bytes + 255) & ~(size_t)255;
    return p;
  };
  _Float16* x16    = (_Float16*)alloc((size_t)MPAD * 128 * 2);
  _Float16* feat16 = (_Float16*)alloc((size_t)MPAD * 256 * 2);   // GEMM out / agg in
  _Float16* hagg16 = (_Float16*)alloc((size_t)MPAD * 256 * 2);   // agg out / GEMM in
  short*    featL3 = (short*)alloc((size_t)MPAD * 64 * 2);
  _Float16* w1f    = (_Float16*)alloc((size_t)256 * 128 * 2);
  _Float16* w2f    = (_Float16*)alloc((size_t)256 * 256 * 2);
  _Float16* w3f    = (_Float16*)alloc((size_t)64 * 256 * 2);
  float* asrc    = (float*)alloc((size_t)n * 4 * 4);
  float* adst    = (float*)alloc((size_t)n * 4 * 4);
  int*   ssrc    = (int*)alloc((size_t)(etot + 4) * 4);
  int*   offsets = (int*)alloc((size_t)(n + 1) * 4);
  int*   cursor  = (int*)alloc((size_t)n * 4);
  int*   counts  = (int*)alloc((size_t)n * 4);
  int*   bsum    = (int*)alloc((size_t)64 * 4);

  const int* esrc = ei;
  const int* edst = ei + e800;
  const int nbScan = (n + 1024) / 1024;

  hipMemsetAsync(counts, 0, (size_t)n * 4, stream);
  hist_kernel<<<(e800 + 255) / 256, 256, 0, stream>>>(edst, e800, counts);
  block_sum_kernel<<<nbScan, 1024, 0, stream>>>(counts, bsum, n);
  scan_sums_kernel<<<1, 64, 0, stream>>>(bsum, nbScan);
  scan_final_kernel<<<nbScan, 1024, 0, stream>>>(counts, bsum, offsets, cursor, n);
  scatter_kernel<<<(etot + 255) / 256, 256, 0, stream>>>(esrc, edst, e800, etot, cursor, ssrc);

  const int nx4 = n * 128 / 4;
  cvt_all_kernel<<<(nx4 + 28672 + 255) / 256, 256, 0, stream>>>(
      x, W1, W2, W3, x16, w1f, w2f, w3f, nx4);

  const int mBlocks = MPAD / 128;  // 391

  // layer 1: fp16 GEMM K=128, alpha fused, fp16 [node][256] out
  gemm2_kernel<128, 128, 128, 2, 2, 256, 4, true><<<dim3(mBlocks, 2), 256, 0, stream>>>(
      x16, w1f, feat16, as1, ad1, asrc, adst, n);
  aggregate4_kernel<<<(n + 7) / 8, 256, 0, stream>>>(
      feat16, asrc, adst, b1, offsets, ssrc, hagg16, n);

  // layer 2: fp16 GEMM K=256, alpha fused, fp16 [node][256] out
  gemm2_kernel<256, 128, 128, 2, 2, 256, 4, true><<<dim3(mBlocks, 2), 256, 0, stream>>>(
      hagg16, w2f, feat16, as2, ad2, asrc, adst, n);
  aggregate4_kernel<<<(n + 7) / 8, 256, 0, stream>>>(
      feat16, asrc, adst, b2, offsets, ssrc, hagg16, n);

  // layer 3: fp16 GEMM K=256, alpha fused, int16 features out
  gemm2_kernel<256, 128, 64, 4, 1, 64, 1, false><<<dim3(mBlocks, 1), 256, 0, stream>>>(
      hagg16, w3f, featL3, as3, ad3, asrc, adst, n);
  aggregate1_kernel<<<(n + 3) / 4, 256, 0, stream>>>(
      featL3, asrc, adst, b3, offsets, ssrc, out, n);
}